// Round 1
// baseline (10052.417 us; speedup 1.0000x reference)
//
#include <hip/hip_runtime.h>

// ---------------------------------------------------------------------------
// DualMemoryLayer (entmax1.5 dual-memory scan), MI355X / gfx950
// Structure:
//   gemm_tn<0>: xz = x @ W_in.T  -> XP = silu(xz[:, :512]), SZ = silu(xz[:, 512:])
//   gemm_tn<1>: XW = XP @ W_x.T
//   scan_kernel: persistent, 8 WGs per batch element, weights in registers,
//                2 device-scope batch barriers per step.  Writes Y = h*silu(z),
//                tape_f, work_f.
//   gemm_tn<1>: out = Y @ W_out.T
// ---------------------------------------------------------------------------

#define BB 8
#define TT 1024
#define DD 512
#define NS 32
#define KW 8        // workgroups per batch
#define SL 64       // DD / KW  (d-slice per WG)
#define TPAD 65     // padded tape row stride (bank-conflict free)

static constexpr float SCALE = 0.044194173824159216f; // 1/sqrt(512)

__device__ __forceinline__ float siluf(float v) { return v / (1.0f + __expf(-v)); }

// ---- cross-lane helpers ----------------------------------------------------
template <int CTRL>
__device__ __forceinline__ float dpp_add(float x) {
  int xi = __builtin_bit_cast(int, x);
  int yi = __builtin_amdgcn_update_dpp(0, xi, CTRL, 0xF, 0xF, false);
  return x + __builtin_bit_cast(float, yi);
}
__device__ __forceinline__ float swz_xor16_add(float x) {
  int yi = __builtin_amdgcn_ds_swizzle(__builtin_bit_cast(int, x), 0x401F); // lane ^= 16 (within 32)
  return x + __builtin_bit_cast(float, yi);
}
// sum over each 32-lane half of the wave; every lane of the half gets the sum
__device__ __forceinline__ float reduce32(float x) {
  x = dpp_add<0x121>(x); // row_ror:1
  x = dpp_add<0x122>(x); // row_ror:2
  x = dpp_add<0x124>(x); // row_ror:4
  x = dpp_add<0x128>(x); // row_ror:8  -> 16-lane row sums
  return swz_xor16_add(x);
}

// ---- exact 1.5-entmax over 32 values held one-per-lane (width-32 segments) --
// input: raw (already scaled) score for index l32; returns p = max(x - tau*,0)^2
__device__ __forceinline__ float entmax32(float z, int l32) {
  float x = 0.5f * z;
  float m = x;
  #pragma unroll
  for (int d = 1; d < 32; d <<= 1) m = fmaxf(m, __shfl_xor(m, d, 32));
  x -= m;
  // bitonic sort DESCENDING across the 32-lane segment
  float s = x;
  #pragma unroll
  for (int k = 2; k <= 32; k <<= 1) {
    #pragma unroll
    for (int j = k >> 1; j > 0; j >>= 1) {
      float y    = __shfl_xor(s, j, 32);
      bool lower = (l32 & j) == 0;
      bool desc  = (l32 & k) == 0;
      s = (desc ^ lower) ? fminf(s, y) : fmaxf(s, y);
    }
  }
  // inclusive prefix sums of zs and zs^2 (Hillis-Steele)
  float cs = s, cq = s * s;
  #pragma unroll
  for (int d = 1; d < 32; d <<= 1) {
    float ts = __shfl_up(cs, d, 32);
    float tq = __shfl_up(cq, d, 32);
    if (l32 >= d) { cs += ts; cq += tq; }
  }
  float kf    = (float)(l32 + 1);
  float mean  = cs / kf;
  float msq   = cq / kf;
  float ssv   = kf * (msq - mean * mean);
  float delta = (1.0f - ssv) / kf;
  float tau   = mean - sqrtf(fmaxf(delta, 0.0f));
  unsigned long long mask = __ballot(tau <= s);
  int support = __popcll(mask & 0xFFFFFFFFull) - 1;
  float tau_star = __shfl(tau, support, 32);
  float p = fmaxf(x - tau_star, 0.0f);
  return p * p;
}

// ---- device-scope batch barrier (monotonic counter, never reset) -----------
__device__ __forceinline__ void batch_barrier(int* cb, int target) {
  __syncthreads(); // all threads done with prior LDS/global work (vmcnt drained)
  if (threadIdx.x == 0) {
    __hip_atomic_fetch_add(cb, 1, __ATOMIC_RELEASE, __HIP_MEMORY_SCOPE_AGENT);
    while (__hip_atomic_load(cb, __ATOMIC_ACQUIRE, __HIP_MEMORY_SCOPE_AGENT) < target) {}
  }
  __syncthreads();
}

// ---------------------------------------------------------------------------
// Tiled fp32 GEMM:  C[M,N] = A[M,K] @ B[N,K]^T     (both K-contiguous)
// MODE 0: silu epilogue split into C0 (cols<512) / C1 (cols>=512), stride 512
// MODE 1: plain write to C0 with row stride N
// ---------------------------------------------------------------------------
template <int MODE>
__global__ __launch_bounds__(256) void gemm_tn(const float* __restrict__ A,
                                               const float* __restrict__ Bm,
                                               float* __restrict__ C0,
                                               float* __restrict__ C1,
                                               int M, int N, int K) {
  const int bm = blockIdx.x, bn = blockIdx.y;
  const int tid = threadIdx.x;
  const int tx = tid & 15, ty = tid >> 4;
  __shared__ __align__(16) float As[16][132];
  __shared__ __align__(16) float Bs[16][132];
  float acc[8][8] = {};
  const int rowA0 = bm * 128, rowB0 = bn * 128;

  for (int k0 = 0; k0 < K; k0 += 16) {
    #pragma unroll
    for (int q = 0; q < 2; ++q) {
      int idx = tid + q * 256;           // 0..511 float4-id
      int r   = idx >> 2;
      int kq  = (idx & 3) * 4;
      float4 a4 = *(const float4*)&A [(size_t)(rowA0 + r) * K + k0 + kq];
      float4 b4 = *(const float4*)&Bm[(size_t)(rowB0 + r) * K + k0 + kq];
      As[kq + 0][r] = a4.x; As[kq + 1][r] = a4.y; As[kq + 2][r] = a4.z; As[kq + 3][r] = a4.w;
      Bs[kq + 0][r] = b4.x; Bs[kq + 1][r] = b4.y; Bs[kq + 2][r] = b4.z; Bs[kq + 3][r] = b4.w;
    }
    __syncthreads();
    #pragma unroll
    for (int kk = 0; kk < 16; ++kk) {
      float4 a0 = *(const float4*)&As[kk][ty * 8];
      float4 a1 = *(const float4*)&As[kk][ty * 8 + 4];
      float4 b0 = *(const float4*)&Bs[kk][tx * 8];
      float4 b1 = *(const float4*)&Bs[kk][tx * 8 + 4];
      float av[8] = {a0.x, a0.y, a0.z, a0.w, a1.x, a1.y, a1.z, a1.w};
      float bv[8] = {b0.x, b0.y, b0.z, b0.w, b1.x, b1.y, b1.z, b1.w};
      #pragma unroll
      for (int i = 0; i < 8; ++i)
        #pragma unroll
        for (int j = 0; j < 8; ++j) acc[i][j] = fmaf(av[i], bv[j], acc[i][j]);
    }
    __syncthreads();
  }
  #pragma unroll
  for (int i = 0; i < 8; ++i) {
    int gr = rowA0 + ty * 8 + i;
    #pragma unroll
    for (int j = 0; j < 8; ++j) {
      int gc = rowB0 + tx * 8 + j;
      float v = acc[i][j];
      if (MODE == 0) {
        float sv = siluf(v);
        if (gc < 512) C0[(size_t)gr * 512 + gc]       = sv;
        else          C1[(size_t)gr * 512 + (gc - 512)] = sv;
      } else {
        C0[(size_t)gr * N + gc] = v;
      }
    }
  }
}

// ---------------------------------------------------------------------------
// Persistent scan kernel.  64 WGs x 1024 threads.  WG (b = blk&7, g = blk>>3)
// owns rows [g*64, g*64+64) of W_h and W_write (in registers) and the matching
// tape slice.  Per step: fused matvec on h_{t-1} -> (h_pre slice, wval slice);
// partial dots ws/q1/q2 -> barrier Sa -> reduce, entmax(b), tape update,
// rs = (1-b)q1 + b q2, entmax(a), read, h_t = tanh(...) -> barrier Sb (h bcast).
// ---------------------------------------------------------------------------
__global__ __launch_bounds__(1024) void scan_kernel(
    const float* __restrict__ Wh, const float* __restrict__ Ww,
    const float* __restrict__ bh, const float* __restrict__ XW,
    const float* __restrict__ SZ, float* __restrict__ Y,
    float* __restrict__ Hg, float* __restrict__ WSp,
    float* __restrict__ Q1p, float* __restrict__ Q2p,
    int* __restrict__ cnt,
    float* __restrict__ outTape, float* __restrict__ outWork) {
  const int tid  = threadIdx.x;
  const int wv   = tid >> 6, lane = tid & 63;
  const int b    = blockIdx.x & 7, g = blockIdx.x >> 3;
  const int h32  = lane >> 5, l32 = lane & 31;
  const int c0   = l32 * 16;

  __shared__ __align__(16) float h_full[DD];
  __shared__ float tape[NS * TPAD];
  __shared__ float hp[SL], wvv[SL], bhs[SL];
  __shared__ float red_ws[NS], red_q1[NS], red_q2;
  __shared__ float bArr[NS], aArr[NS];

  // stationary weights: 4 rows x 16 cols per thread (rl = 8*wv + 4*h32 + i)
  float w[4][16];
  #pragma unroll
  for (int i = 0; i < 4; ++i) {
    int rl = 8 * wv + 4 * h32 + i;
    const float* src = (rl < 64) ? (Wh + (size_t)(g * 64 + rl) * DD)
                                 : (Ww + (size_t)(g * 64 + rl - 64) * DD);
    #pragma unroll
    for (int q = 0; q < 4; ++q) {
      float4 v4 = *(const float4*)&src[c0 + 4 * q];
      w[i][4 * q + 0] = v4.x; w[i][4 * q + 1] = v4.y;
      w[i][4 * q + 2] = v4.z; w[i][4 * q + 3] = v4.w;
    }
  }
  for (int e = tid; e < DD; e += 1024) h_full[e] = 0.0f;
  for (int e = tid; e < NS * TPAD; e += 1024) tape[e] = 0.0f;
  if (tid < SL) bhs[tid] = bh[g * SL + tid];
  __syncthreads();

  int bar = 0;
  int* cb = cnt + b;

  for (int t = 0; t <= TT; ++t) {
    // ---- fused matvec: [Wh;Ww] @ h_{t-1} ----
    float hv[16];
    #pragma unroll
    for (int q = 0; q < 4; ++q) {
      float4 v4 = *(const float4*)&h_full[c0 + 4 * q];
      hv[4 * q + 0] = v4.x; hv[4 * q + 1] = v4.y;
      hv[4 * q + 2] = v4.z; hv[4 * q + 3] = v4.w;
    }
    float a0 = 0.f, a1 = 0.f, a2 = 0.f, a3 = 0.f;
    #pragma unroll
    for (int j = 0; j < 16; ++j) {
      a0 = fmaf(w[0][j], hv[j], a0);
      a1 = fmaf(w[1][j], hv[j], a1);
      a2 = fmaf(w[2][j], hv[j], a2);
      a3 = fmaf(w[3][j], hv[j], a3);
    }
    a0 = reduce32(a0); a1 = reduce32(a1); a2 = reduce32(a2); a3 = reduce32(a3);
    if (l32 < 4) {
      float v = a0;
      v = (l32 == 1) ? a1 : v;
      v = (l32 == 2) ? a2 : v;
      v = (l32 == 3) ? a3 : v;
      int rl = 8 * wv + 4 * h32 + l32;
      if (rl < 64) hp[rl] = v; else wvv[rl - 64] = v;
    }
    __syncthreads();
    // ---- h_pre = mv + xw_t + b_h ----
    if (t < TT && tid < SL)
      hp[tid] += XW[(size_t)(b * TT + t) * DD + g * SL + tid] + bhs[tid];
    __syncthreads();
    // ---- partial dots over this WG's d-slice ----
    if (wv == 0) { // ws_{t-1}[n] = tape_{t-1}[n,:] . h_{t-1}
      int n = lane >> 1, dp = lane & 1;
      float s = 0.f;
      #pragma unroll
      for (int j = 0; j < 32; ++j)
        s = fmaf(tape[n * TPAD + dp + 2 * j], h_full[g * SL + dp + 2 * j], s);
      s = dpp_add<0x00B1>(s); // + partner (lane^1)
      if (dp == 0)
        __hip_atomic_store(&WSp[(b * KW + g) * NS + n], s, __ATOMIC_RELAXED, __HIP_MEMORY_SCOPE_AGENT);
    } else if (wv == 1 && t < TT) { // q1[n] = tape_{t-1}[n,:] . h_pre
      int n = lane >> 1, dp = lane & 1;
      float s = 0.f;
      #pragma unroll
      for (int j = 0; j < 32; ++j)
        s = fmaf(tape[n * TPAD + dp + 2 * j], hp[dp + 2 * j], s);
      s = dpp_add<0x00B1>(s);
      if (dp == 0)
        __hip_atomic_store(&Q1p[(b * KW + g) * NS + n], s, __ATOMIC_RELAXED, __HIP_MEMORY_SCOPE_AGENT);
    } else if (wv == 2 && t < TT) { // q2 = wval . h_pre
      float s = fmaf(wvv[l32], hp[l32], wvv[l32 + 32] * hp[l32 + 32]);
      s = reduce32(s);
      if (lane == 0)
        __hip_atomic_store(&Q2p[b * KW + g], s, __ATOMIC_RELAXED, __HIP_MEMORY_SCOPE_AGENT);
    }
    bar += KW;
    batch_barrier(cb, bar); // Sa
    // ---- reduce partials across the batch's KW WGs ----
    if (tid < NS) {
      float s = 0.f;
      #pragma unroll
      for (int k = 0; k < KW; ++k)
        s += __hip_atomic_load(&WSp[(b * KW + k) * NS + tid], __ATOMIC_RELAXED, __HIP_MEMORY_SCOPE_AGENT);
      red_ws[tid] = s * SCALE;
    } else if (tid >= 64 && tid < 64 + NS && t < TT) {
      float s = 0.f;
      #pragma unroll
      for (int k = 0; k < KW; ++k)
        s += __hip_atomic_load(&Q1p[(b * KW + k) * NS + (tid - 64)], __ATOMIC_RELAXED, __HIP_MEMORY_SCOPE_AGENT);
      red_q1[tid - 64] = s;
    } else if (tid == 96 && t < TT) {
      float s = 0.f;
      #pragma unroll
      for (int k = 0; k < KW; ++k)
        s += __hip_atomic_load(&Q2p[b * KW + k], __ATOMIC_RELAXED, __HIP_MEMORY_SCOPE_AGENT);
      red_q2 = s;
    }
    __syncthreads();
    // ---- entmax(b_{t-1}) ----
    float pb = 0.0f;
    if (wv == 0) {
      pb = entmax32(red_ws[l32], l32);
      if (lane < NS) bArr[lane] = pb;
    }
    __syncthreads();
    // ---- wave0: rs + entmax(a_t);  others: tape update T_{t-1} -> T_t ----
    if (wv == 0) {
      if (t < TT) {
        float rs = SCALE * fmaf(pb, red_q2 - red_q1[l32], red_q1[l32]);
        float pa = entmax32(rs, l32);
        if (lane < NS) aArr[lane] = pa;
      }
    } else {
      for (int e = tid - 64; e < NS * SL; e += 960) {
        int n = e >> 6, d = e & 63;
        float bn = bArr[n];
        float tv = tape[n * TPAD + d];
        tape[n * TPAD + d] = fmaf(bn, wvv[d] - tv, tv);
      }
    }
    __syncthreads();
    if (t == TT) { // final outputs: tape_f = T_T, work_f = h_{T-1}
      if (tid < SL) outWork[b * DD + g * SL + tid] = h_full[g * SL + tid];
      for (int e = tid; e < NS * SL; e += 1024) {
        int n = e >> 6, d = e & 63;
        outTape[(size_t)(b * NS + n) * DD + g * SL + d] = tape[n * TPAD + d];
      }
      break;
    }
    // ---- read + h_t = tanh(h_pre + read) ----
    if (tid < SL) {
      float r = 0.f;
      #pragma unroll
      for (int n = 0; n < NS; ++n) r = fmaf(aArr[n], tape[n * TPAD + tid], r);
      float hn = tanhf(hp[tid] + r);
      size_t yi = (size_t)(b * TT + t) * DD + g * SL + tid;
      Y[yi] = hn * SZ[yi];
      __hip_atomic_store(&Hg[b * DD + g * SL + tid], hn, __ATOMIC_RELAXED, __HIP_MEMORY_SCOPE_AGENT);
      h_full[g * SL + tid] = hn;
    }
    bar += KW;
    batch_barrier(cb, bar); // Sb (h broadcast)
    if (tid < DD)
      h_full[tid] = __hip_atomic_load(&Hg[b * DD + tid], __ATOMIC_RELAXED, __HIP_MEMORY_SCOPE_AGENT);
    __syncthreads();
  }
}

// ---------------------------------------------------------------------------
extern "C" void kernel_launch(void* const* d_in, const int* in_sizes, int n_in,
                              void* d_out, int out_size, void* d_ws, size_t ws_size,
                              hipStream_t stream) {
  (void)in_sizes; (void)n_in; (void)out_size; (void)ws_size;
  const float* x    = (const float*)d_in[0];
  const float* W_in = (const float*)d_in[1];
  const float* W_out= (const float*)d_in[2];
  const float* W_h  = (const float*)d_in[3];
  const float* W_x  = (const float*)d_in[4];
  const float* b_h  = (const float*)d_in[5];
  const float* W_wr = (const float*)d_in[6];

  float* out     = (float*)d_out;                     // [B,T,D]
  float* outTape = out + (size_t)BB * TT * DD;        // [B,NS,D]
  float* outWork = outTape + (size_t)BB * NS * DD;    // [B,D]

  float* wsf = (float*)d_ws;
  int*   cnt = (int*)d_ws;            // 8 counters (first 64 B zeroed below)
  float* Hg  = wsf + 64;              // [B][512]
  float* WSp = wsf + 4224;            // [B][KW][NS]
  float* Q1p = wsf + 6272;            // [B][KW][NS]
  float* Q2p = wsf + 8320;            // [B][KW]
  float* XP  = wsf + 16384;           // [8192,512]  (reused as Y by scan)
  float* SZ  = XP + (size_t)BB * TT * DD;
  float* XWb = SZ + (size_t)BB * TT * DD;

  hipMemsetAsync(cnt, 0, 64, stream);

  // xz = x @ W_in.T -> XP = silu(lo), SZ = silu(hi)
  gemm_tn<0><<<dim3(64, 8), 256, 0, stream>>>(x, W_in, XP, SZ, BB * TT, 2 * DD, DD);
  // XW = XP @ W_x.T
  gemm_tn<1><<<dim3(64, 4), 256, 0, stream>>>(XP, W_x, XWb, nullptr, BB * TT, DD, DD);
  // sequential scan (writes Y into XP region, plus tape_f / work_f)
  scan_kernel<<<64, 1024, 0, stream>>>(W_h, W_wr, b_h, XWb, SZ, XP,
                                       Hg, WSp, Q1p, Q2p, cnt, outTape, outWork);
  // out = Y @ W_out.T
  gemm_tn<1><<<dim3(64, 4), 256, 0, stream>>>(XP, W_out, out, nullptr, BB * TT, DD, DD);
}

// Round 2
// 9189.527 us; speedup vs baseline: 1.0939x; 1.0939x over previous
//
#include <hip/hip_runtime.h>

// ---------------------------------------------------------------------------
// DualMemoryLayer (entmax1.5 dual-memory scan), MI355X / gfx950
//   gemm_tn<0>: xz = x @ W_in.T -> XP = silu(lo), SZ = silu(hi)
//   gemm_tn<1>: XW = XP @ W_x.T
//   scan_kernel: 64 persistent WGs (8 per batch), column-sliced weights in
//     registers, FULL tape replicated per WG in LDS, ONE flag-barrier/step.
//   gemm_tn<1>: out = Y @ W_out.T
// ---------------------------------------------------------------------------

#define BB 8
#define TT 1024
#define DD 512
#define NS 32
#define KW 8          // workgroups per batch
#define FSTRIDE 256   // ints between flags (1 KB) — no shared cache lines

static constexpr float SCALE = 0.044194173824159216f; // 1/sqrt(512)

__device__ __forceinline__ float siluf(float v) { return v / (1.0f + __expf(-v)); }

// ---- cross-lane helpers ----------------------------------------------------
template <int CTRL>
__device__ __forceinline__ float dpp_add(float x) {
  int xi = __builtin_bit_cast(int, x);
  int yi = __builtin_amdgcn_update_dpp(0, xi, CTRL, 0xF, 0xF, false);
  return x + __builtin_bit_cast(float, yi);
}
__device__ __forceinline__ float swz_xor16_add(float x) {
  int yi = __builtin_amdgcn_ds_swizzle(__builtin_bit_cast(int, x), 0x401F);
  return x + __builtin_bit_cast(float, yi);
}
// sum over each 32-lane half; every lane of the half gets the sum
__device__ __forceinline__ float reduce32(float x) {
  x = dpp_add<0x121>(x);
  x = dpp_add<0x122>(x);
  x = dpp_add<0x124>(x);
  x = dpp_add<0x128>(x);
  return swz_xor16_add(x);
}

// ---- exact 1.5-entmax over 32 values, one per lane (width-32 segments) -----
__device__ __forceinline__ float entmax32(float z, int l32) {
  float x = 0.5f * z;
  float m = x;
  #pragma unroll
  for (int d = 1; d < 32; d <<= 1) m = fmaxf(m, __shfl_xor(m, d, 32));
  x -= m;
  float s = x; // bitonic sort descending
  #pragma unroll
  for (int k = 2; k <= 32; k <<= 1) {
    #pragma unroll
    for (int j = k >> 1; j > 0; j >>= 1) {
      float y    = __shfl_xor(s, j, 32);
      bool lower = (l32 & j) == 0;
      bool desc  = (l32 & k) == 0;
      s = (desc ^ lower) ? fminf(s, y) : fmaxf(s, y);
    }
  }
  float cs = s, cq = s * s; // inclusive prefix sums
  #pragma unroll
  for (int d = 1; d < 32; d <<= 1) {
    float ts = __shfl_up(cs, d, 32);
    float tq = __shfl_up(cq, d, 32);
    if (l32 >= d) { cs += ts; cq += tq; }
  }
  float kf    = (float)(l32 + 1);
  float mean  = cs / kf;
  float msq   = cq / kf;
  float ssv   = kf * (msq - mean * mean);
  float delta = (1.0f - ssv) / kf;
  float tau   = mean - sqrtf(fmaxf(delta, 0.0f));
  unsigned long long mask = __ballot(tau <= s);
  int support = __popcll(mask & 0xFFFFFFFFull) - 1;
  float tau_star = __shfl(tau, support, 32);
  float p = fmaxf(x - tau_star, 0.0f);
  return p * p;
}

// ---------------------------------------------------------------------------
// Tiled fp32 GEMM:  C[M,N] = A[M,K] @ B[N,K]^T
// ---------------------------------------------------------------------------
template <int MODE>
__global__ __launch_bounds__(256) void gemm_tn(const float* __restrict__ A,
                                               const float* __restrict__ Bm,
                                               float* __restrict__ C0,
                                               float* __restrict__ C1,
                                               int M, int N, int K) {
  const int bm = blockIdx.x, bn = blockIdx.y;
  const int tid = threadIdx.x;
  const int tx = tid & 15, ty = tid >> 4;
  __shared__ __align__(16) float As[16][132];
  __shared__ __align__(16) float Bs[16][132];
  float acc[8][8] = {};
  const int rowA0 = bm * 128, rowB0 = bn * 128;

  for (int k0 = 0; k0 < K; k0 += 16) {
    #pragma unroll
    for (int q = 0; q < 2; ++q) {
      int idx = tid + q * 256;
      int r   = idx >> 2;
      int kq  = (idx & 3) * 4;
      float4 a4 = *(const float4*)&A [(size_t)(rowA0 + r) * K + k0 + kq];
      float4 b4 = *(const float4*)&Bm[(size_t)(rowB0 + r) * K + k0 + kq];
      As[kq + 0][r] = a4.x; As[kq + 1][r] = a4.y; As[kq + 2][r] = a4.z; As[kq + 3][r] = a4.w;
      Bs[kq + 0][r] = b4.x; Bs[kq + 1][r] = b4.y; Bs[kq + 2][r] = b4.z; Bs[kq + 3][r] = b4.w;
    }
    __syncthreads();
    #pragma unroll
    for (int kk = 0; kk < 16; ++kk) {
      float4 a0 = *(const float4*)&As[kk][ty * 8];
      float4 a1 = *(const float4*)&As[kk][ty * 8 + 4];
      float4 b0 = *(const float4*)&Bs[kk][tx * 8];
      float4 b1 = *(const float4*)&Bs[kk][tx * 8 + 4];
      float av[8] = {a0.x, a0.y, a0.z, a0.w, a1.x, a1.y, a1.z, a1.w};
      float bv[8] = {b0.x, b0.y, b0.z, b0.w, b1.x, b1.y, b1.z, b1.w};
      #pragma unroll
      for (int i = 0; i < 8; ++i)
        #pragma unroll
        for (int j = 0; j < 8; ++j) acc[i][j] = fmaf(av[i], bv[j], acc[i][j]);
    }
    __syncthreads();
  }
  #pragma unroll
  for (int i = 0; i < 8; ++i) {
    int gr = rowA0 + ty * 8 + i;
    #pragma unroll
    for (int j = 0; j < 8; ++j) {
      int gc = rowB0 + tx * 8 + j;
      float v = acc[i][j];
      if (MODE == 0) {
        float sv = siluf(v);
        if (gc < 512) C0[(size_t)gr * 512 + gc]         = sv;
        else          C1[(size_t)gr * 512 + (gc - 512)] = sv;
      } else {
        C0[(size_t)gr * N + gc] = v;
      }
    }
  }
}

// ---------------------------------------------------------------------------
// Persistent scan.  WG (b = blk&7, g = blk>>3), 1024 threads.
// WG g holds cols [64g,64g+64) of [W_h; W_write] in registers (row r =
// wv*64+lane, 64 floats) and a FULL replicated tape in LDS.
// Per step: partial mv from own h-slice -> publish 1024 partials ->
// ONE flag barrier -> gather full h_pre/wval -> local ws/q1/q2, entmax(b),
// tape update, entmax(a), read, h = tanh(...).  No atomic RMW anywhere.
// ---------------------------------------------------------------------------
__global__ __launch_bounds__(1024) void scan_kernel(
    const float* __restrict__ Wh, const float* __restrict__ Ww,
    const float* __restrict__ bh, const float* __restrict__ XW,
    const float* __restrict__ SZ, float* __restrict__ Y,
    float* __restrict__ Pp,      // [2][BB][KW][1024] partial matvec buffers
    int* __restrict__ flags,     // [BB*KW*FSTRIDE]
    float* __restrict__ outTape, float* __restrict__ outWork) {
  const int tid  = threadIdx.x;
  const int wv   = tid >> 6, lane = tid & 63;
  const int b    = blockIdx.x & 7, g = blockIdx.x >> 3;
  const int l32  = lane & 31;

  __shared__ float tape[NS][DD];      // full tape replica
  __shared__ __align__(16) float h_full[DD];
  __shared__ float hp[DD], wvv[DD], bhs[DD];
  __shared__ float ws_arr[NS], q1_arr[NS], q2s;
  __shared__ float bArr[NS], aArr[NS];

  // stationary weights: row r = wv*64+lane, cols g*64 .. g*64+63
  float w[64];
  {
    int r = wv * 64 + lane;
    const float* src = (r < DD) ? (Wh + (size_t)r * DD + g * 64)
                                : (Ww + (size_t)(r - DD) * DD + g * 64);
    #pragma unroll
    for (int q = 0; q < 16; ++q) {
      float4 v4 = *(const float4*)(src + 4 * q);
      w[4*q+0] = v4.x; w[4*q+1] = v4.y; w[4*q+2] = v4.z; w[4*q+3] = v4.w;
    }
  }
  for (int e = tid; e < NS * DD; e += 1024) ((float*)tape)[e] = 0.f;
  if (tid < DD) { h_full[tid] = 0.f; bhs[tid] = bh[tid]; }
  __syncthreads();

  int*       myflag = flags + (b * KW + g) * FSTRIDE;
  const int* bflags = flags + b * KW * FSTRIDE;

  for (int t = 0; t <= TT; ++t) {
    // ---- partial matvec: cols slice of [Wh;Ww] times own h slice ----
    float pv = 0.f;
    #pragma unroll
    for (int q = 0; q < 16; ++q) {
      float4 h4 = *(const float4*)&h_full[g * 64 + 4 * q];
      pv = fmaf(w[4*q+0], h4.x, pv);
      pv = fmaf(w[4*q+1], h4.y, pv);
      pv = fmaf(w[4*q+2], h4.z, pv);
      pv = fmaf(w[4*q+3], h4.w, pv);
    }
    {
      float* buf = Pp + ((size_t)(t & 1) * BB * KW + (size_t)b * KW + g) * 1024;
      __hip_atomic_store(&buf[wv * 64 + lane], pv, __ATOMIC_RELAXED, __HIP_MEMORY_SCOPE_AGENT);
    }
    // prefetch step inputs (independent of the barrier)
    float x_in = 0.f, szv = 0.f;
    if (t < TT && tid < DD) {
      x_in = XW[((size_t)b * TT + t) * DD + tid];
      if ((tid >> 6) == g) szv = SZ[((size_t)b * TT + t) * DD + tid];
    }
    __syncthreads();                       // all partial stores drained (vmcnt0)
    if (tid == 0)
      __hip_atomic_store(myflag, t + 1, __ATOMIC_RELEASE, __HIP_MEMORY_SCOPE_AGENT);
    if (wv == 0 && lane < KW) {            // 8 lanes, one flag each
      while (__hip_atomic_load(bflags + lane * FSTRIDE, __ATOMIC_ACQUIRE,
                               __HIP_MEMORY_SCOPE_AGENT) < t + 1) {}
    }
    __syncthreads();
    // ---- gather: full mv result; hp = mv + xw_t + bh; wvv = W_write h ----
    {
      const float* base = Pp + ((size_t)(t & 1) * BB * KW + (size_t)b * KW) * 1024;
      float s = 0.f;
      #pragma unroll
      for (int k = 0; k < KW; ++k)
        s += __hip_atomic_load(base + k * 1024 + tid, __ATOMIC_RELAXED,
                               __HIP_MEMORY_SCOPE_AGENT);
      if (tid < DD) hp[tid] = s + x_in + bhs[tid];
      else          wvv[tid - DD] = s;
    }
    __syncthreads();
    // ---- local dots: ws = T.h_prev, q1 = T.hp (slot n = wv*2 + half) ----
    {
      int n = wv * 2 + (lane >> 5);
      float sw = 0.f, s1 = 0.f;
      #pragma unroll
      for (int j = 0; j < 16; ++j) {
        float tv = tape[n][l32 + 32 * j];
        sw = fmaf(tv, h_full[l32 + 32 * j], sw);
        s1 = fmaf(tv, hp[l32 + 32 * j], s1);
      }
      sw = reduce32(sw); s1 = reduce32(s1);
      if (l32 == 0) { ws_arr[n] = sw; q1_arr[n] = s1; }
    }
    if (wv == 0) {                          // q2 = wvv . hp
      float s2 = 0.f;
      #pragma unroll
      for (int j = 0; j < 8; ++j)
        s2 = fmaf(wvv[lane + 64 * j], hp[lane + 64 * j], s2);
      s2 = reduce32(s2);
      s2 += __shfl_xor(s2, 32, 64);
      if (lane == 0) q2s = s2;
    }
    __syncthreads();
    // ---- wave0: entmax(b_{t-1}) then entmax(a_t) ----
    if (wv == 0) {
      float pb = entmax32(ws_arr[l32] * SCALE, l32);
      if (lane < NS) bArr[lane] = pb;
      if (t < TT) {
        float rs = SCALE * fmaf(pb, q2s - q1_arr[l32], q1_arr[l32]);
        float pa = entmax32(rs, l32);
        if (lane < NS) aArr[lane] = pa;
      }
    }
    __syncthreads();
    // ---- tape update + read + h (thread d = tid < 512) ----
    if (tid < DD) {
      float r = 0.f;
      float wvd = wvv[tid];
      #pragma unroll
      for (int n = 0; n < NS; ++n) {
        float tv = tape[n][tid];
        tv = fmaf(bArr[n], wvd - tv, tv);
        tape[n][tid] = tv;
        r = fmaf(aArr[n], tv, r);
      }
      if (t < TT) {
        float hn = tanhf(hp[tid] + r);
        if ((tid >> 6) == g)
          Y[((size_t)b * TT + t) * DD + tid] = hn * szv;
        h_full[tid] = hn;
      }
    }
    if (t == TT) {
      __syncthreads();
      if (tid < DD && (tid >> 6) == g) outWork[(size_t)b * DD + tid] = h_full[tid];
      for (int e = tid; e < NS * 64; e += 1024) {
        int n = e >> 6, d = g * 64 + (e & 63);
        outTape[((size_t)b * NS + n) * DD + d] = tape[n][d];
      }
      break;
    }
    __syncthreads();
  }
}

// ---------------------------------------------------------------------------
extern "C" void kernel_launch(void* const* d_in, const int* in_sizes, int n_in,
                              void* d_out, int out_size, void* d_ws, size_t ws_size,
                              hipStream_t stream) {
  (void)in_sizes; (void)n_in; (void)out_size; (void)ws_size;
  const float* x    = (const float*)d_in[0];
  const float* W_in = (const float*)d_in[1];
  const float* W_out= (const float*)d_in[2];
  const float* W_h  = (const float*)d_in[3];
  const float* W_x  = (const float*)d_in[4];
  const float* b_h  = (const float*)d_in[5];
  const float* W_wr = (const float*)d_in[6];

  float* out     = (float*)d_out;                  // [B,T,D]
  float* outTape = out + (size_t)BB * TT * DD;     // [B,NS,D]
  float* outWork = outTape + (size_t)BB * NS * DD; // [B,D]

  float* wsf  = (float*)d_ws;
  float* XP   = wsf;                               // [8192,512] (Y after scan)
  float* SZ   = XP + (size_t)BB * TT * DD;
  float* XWb  = SZ + (size_t)BB * TT * DD;
  int*   flags= (int*)(XWb + (size_t)BB * TT * DD);           // 64 KB
  float* Pp   = (float*)(flags + BB * KW * FSTRIDE);          // 512 KB

  hipMemsetAsync(flags, 0, BB * KW * FSTRIDE * sizeof(int), stream);

  gemm_tn<0><<<dim3(64, 8), 256, 0, stream>>>(x, W_in, XP, SZ, BB * TT, 2 * DD, DD);
  gemm_tn<1><<<dim3(64, 4), 256, 0, stream>>>(XP, W_x, XWb, nullptr, BB * TT, DD, DD);
  scan_kernel<<<64, 1024, 0, stream>>>(W_h, W_wr, b_h, XWb, SZ, XP,
                                       Pp, flags, outTape, outWork);
  gemm_tn<1><<<dim3(64, 4), 256, 0, stream>>>(XP, W_out, out, nullptr, BB * TT, DD, DD);
}

// Round 6
// 6197.638 us; speedup vs baseline: 1.6220x; 1.4827x over previous
//
#include <hip/hip_runtime.h>

// ---------------------------------------------------------------------------
// DualMemoryLayer (entmax1.5 dual-memory scan), MI355X / gfx950
//   gemm_tn<0>: xz = x @ W_in.T -> XP = silu(lo), SZ = silu(hi)
//   gemm_tn<1>: XW = XP @ W_x.T
//   scan_kernel: 64 persistent WGs (8 per batch), ROW-sliced weights in
//     registers, FULL tape replicated per WG in LDS.  Cross-WG exchange via
//     SELF-VALIDATING stamped 64-bit atomics (stamp|value in one 8B relaxed
//     agent store) — no flags, no fences, no cross-address ordering assumed.
//   gemm_tn<1>: out = Y @ W_out.T
//
// R5 fix vs R4: reduce8 used DPP row_ror with the direction inverted (row_ror
// moves data toward higher lanes), so the aligned 8-sums were at lanes 7/15,
// not 0/8 — seg==0 published row r's segment 0 plus row r+1's segments 1..7
// (deterministic absmax 4.86e-2 in R3 AND R4).  Replaced with a
// direction-proof ds_swizzle XOR butterfly (^1, ^2, ^4).
// R6 fix vs R5: ds_swizzle pattern must be an immediate -> template param.
// ---------------------------------------------------------------------------

#define BB 8
#define TT 1024
#define DD 512
#define NS 32
#define KW 8          // workgroups per batch

static constexpr float SCALE = 0.044194173824159216f; // 1/sqrt(512)

__device__ __forceinline__ float siluf(float v) { return v / (1.0f + __expf(-v)); }

// ---- cross-lane helpers ----------------------------------------------------
template <int CTRL>
__device__ __forceinline__ float dpp_add(float x) {
  int xi = __builtin_bit_cast(int, x);
  int yi = __builtin_amdgcn_update_dpp(0, xi, CTRL, 0xF, 0xF, false);
  return x + __builtin_bit_cast(float, yi);
}
template <int PAT>
__device__ __forceinline__ float swz_add(float x) {
  int yi = __builtin_amdgcn_ds_swizzle(__builtin_bit_cast(int, x), PAT);
  return x + __builtin_bit_cast(float, yi);
}
// direction-proof sum within each aligned 8-lane group (every lane gets it):
// ds_swizzle BitMode xor-masks ^1, ^2, ^4 (patterns per ISA doc)
__device__ __forceinline__ float reduce8(float x) {
  x = swz_add<0x041F>(x); // lane ^= 1
  x = swz_add<0x081F>(x); // lane ^= 2
  x = swz_add<0x101F>(x); // lane ^= 4
  return x;
}
// sum over each 32-lane half; every lane of the half gets the sum
__device__ __forceinline__ float reduce32(float x) {
  x = dpp_add<0x121>(x);
  x = dpp_add<0x122>(x);
  x = dpp_add<0x124>(x);
  x = dpp_add<0x128>(x);
  return swz_add<0x401F>(x); // lane ^= 16
}

// ---- exact 1.5-entmax over 32 values, one per lane (width-32 segments) -----
__device__ __forceinline__ float entmax32(float z, int l32) {
  float x = 0.5f * z;
  float m = x;
  #pragma unroll
  for (int d = 1; d < 32; d <<= 1) m = fmaxf(m, __shfl_xor(m, d, 32));
  x -= m;
  float s = x; // bitonic sort descending
  #pragma unroll
  for (int k = 2; k <= 32; k <<= 1) {
    #pragma unroll
    for (int j = k >> 1; j > 0; j >>= 1) {
      float y    = __shfl_xor(s, j, 32);
      bool lower = (l32 & j) == 0;
      bool desc  = (l32 & k) == 0;
      s = (desc ^ lower) ? fminf(s, y) : fmaxf(s, y);
    }
  }
  float cs = s, cq = s * s; // inclusive prefix sums
  #pragma unroll
  for (int d = 1; d < 32; d <<= 1) {
    float ts = __shfl_up(cs, d, 32);
    float tq = __shfl_up(cq, d, 32);
    if (l32 >= d) { cs += ts; cq += tq; }
  }
  float kf    = (float)(l32 + 1);
  float mean  = cs / kf;
  float msq   = cq / kf;
  float ssv   = kf * (msq - mean * mean);
  float delta = (1.0f - ssv) / kf;
  float tau   = mean - sqrtf(fmaxf(delta, 0.0f));
  unsigned long long mask = __ballot(tau <= s);
  int support = __popcll(mask & 0xFFFFFFFFull) - 1;
  float tau_star = __shfl(tau, support, 32);
  float p = fmaxf(x - tau_star, 0.0f);
  return p * p;
}

// ---------------------------------------------------------------------------
// Tiled fp32 GEMM:  C[M,N] = A[M,K] @ B[N,K]^T
// ---------------------------------------------------------------------------
template <int MODE>
__global__ __launch_bounds__(256) void gemm_tn(const float* __restrict__ A,
                                               const float* __restrict__ Bm,
                                               float* __restrict__ C0,
                                               float* __restrict__ C1,
                                               int M, int N, int K) {
  const int bm = blockIdx.x, bn = blockIdx.y;
  const int tid = threadIdx.x;
  const int tx = tid & 15, ty = tid >> 4;
  __shared__ __align__(16) float As[16][132];
  __shared__ __align__(16) float Bs[16][132];
  float acc[8][8] = {};
  const int rowA0 = bm * 128, rowB0 = bn * 128;

  for (int k0 = 0; k0 < K; k0 += 16) {
    #pragma unroll
    for (int q = 0; q < 2; ++q) {
      int idx = tid + q * 256;
      int r   = idx >> 2;
      int kq  = (idx & 3) * 4;
      float4 a4 = *(const float4*)&A [(size_t)(rowA0 + r) * K + k0 + kq];
      float4 b4 = *(const float4*)&Bm[(size_t)(rowB0 + r) * K + k0 + kq];
      As[kq + 0][r] = a4.x; As[kq + 1][r] = a4.y; As[kq + 2][r] = a4.z; As[kq + 3][r] = a4.w;
      Bs[kq + 0][r] = b4.x; Bs[kq + 1][r] = b4.y; Bs[kq + 2][r] = b4.z; Bs[kq + 3][r] = b4.w;
    }
    __syncthreads();
    #pragma unroll
    for (int kk = 0; kk < 16; ++kk) {
      float4 a0 = *(const float4*)&As[kk][ty * 8];
      float4 a1 = *(const float4*)&As[kk][ty * 8 + 4];
      float4 b0 = *(const float4*)&Bs[kk][tx * 8];
      float4 b1 = *(const float4*)&Bs[kk][tx * 8 + 4];
      float av[8] = {a0.x, a0.y, a0.z, a0.w, a1.x, a1.y, a1.z, a1.w};
      float bv[8] = {b0.x, b0.y, b0.z, b0.w, b1.x, b1.y, b1.z, b1.w};
      #pragma unroll
      for (int i = 0; i < 8; ++i)
        #pragma unroll
        for (int j = 0; j < 8; ++j) acc[i][j] = fmaf(av[i], bv[j], acc[i][j]);
    }
    __syncthreads();
  }
  #pragma unroll
  for (int i = 0; i < 8; ++i) {
    int gr = rowA0 + ty * 8 + i;
    #pragma unroll
    for (int j = 0; j < 8; ++j) {
      int gc = rowB0 + tx * 8 + j;
      float v = acc[i][j];
      if (MODE == 0) {
        float sv = siluf(v);
        if (gc < 512) C0[(size_t)gr * 512 + gc]         = sv;
        else          C1[(size_t)gr * 512 + (gc - 512)] = sv;
      } else {
        C0[(size_t)gr * N + gc] = v;
      }
    }
  }
}

// ---------------------------------------------------------------------------
// Persistent scan.  WG (b = blk&7, g = blk>>3), 1024 threads.
// WG g owns fused rows [g*128, g*128+128) of [W_h; W_write] in registers
// (8 threads per row, 64 cols each, bank-swizzled) and a FULL replicated
// tape in LDS.  Per step: row-slice matvec -> publish 128 stamped 8B values
// -> overlap ws-dots + entmax(b) -> each thread POLLS ITS OWN element until
// stamp==t+1 (value from the same atomic load -> no ordering assumptions) ->
// q1/q2, entmax(a) || tape update, read, h = tanh(...).
// Overwrite safety: parity double-buffer + transitive gather dependency.
// ---------------------------------------------------------------------------
__global__ __launch_bounds__(1024) void scan_kernel(
    const float* __restrict__ Wh, const float* __restrict__ Ww,
    const float* __restrict__ bh, const float* __restrict__ XW,
    const float* __restrict__ SZ, float* __restrict__ Y,
    unsigned long long* __restrict__ Pp,  // [2][BB][1024] stamped values
    float* __restrict__ outTape, float* __restrict__ outWork) {
  const int tid  = threadIdx.x;
  const int wv   = tid >> 6, lane = tid & 63;
  const int b    = blockIdx.x & 7, g = blockIdx.x >> 3;
  const int l32  = lane & 31;
  const int seg  = lane & 7;        // column segment (8 per row)
  const int row  = tid >> 3;        // local row 0..127
  const int frow = g * 128 + row;   // fused row 0..1023

  __shared__ float tape[NS][DD];    // full tape replica
  __shared__ float h_full[DD], hp[DD], wvv[DD], bhs[DD];
  __shared__ float ws_arr[NS], q1_arr[NS], q2s;
  __shared__ float bArr[NS], aArr[NS];

  // stationary weights: 64 floats = row `frow`, cols seg*64..seg*64+63,
  // loaded in bank-swizzled order (rotate by 4*seg floats within the segment)
  float w[64];
  {
    const float* src = (frow < DD) ? (Wh + (size_t)frow * DD)
                                   : (Ww + (size_t)(frow - DD) * DD);
    #pragma unroll
    for (int q = 0; q < 16; ++q) {
      int c4 = seg * 64 + ((4 * q + 4 * seg) & 63);
      float4 v4 = *(const float4*)(src + c4);
      w[4*q+0] = v4.x; w[4*q+1] = v4.y; w[4*q+2] = v4.z; w[4*q+3] = v4.w;
    }
  }
  for (int e = tid; e < NS * DD; e += 1024) ((float*)tape)[e] = 0.f;
  if (tid < DD) { h_full[tid] = 0.f; bhs[tid] = bh[tid]; }
  __syncthreads();

  for (int t = 0; t <= TT; ++t) {
    unsigned long long* pbuf = Pp + ((size_t)(t & 1) * BB + b) * 1024;
    // ---- row-slice matvec: pv = sum over my 64 cols of W[frow]*h ----
    float pv = 0.f;
    #pragma unroll
    for (int q = 0; q < 16; ++q) {
      int c4 = seg * 64 + ((4 * q + 4 * seg) & 63);   // bank-conflict-free
      float4 h4 = *(const float4*)&h_full[c4];
      pv = fmaf(w[4*q+0], h4.x, pv);
      pv = fmaf(w[4*q+1], h4.y, pv);
      pv = fmaf(w[4*q+2], h4.z, pv);
      pv = fmaf(w[4*q+3], h4.w, pv);
    }
    pv = reduce8(pv);            // xor butterfly: every lane has the row sum
    if (seg == 0) {
      unsigned long long u =
          ((unsigned long long)(unsigned)(t + 1) << 32) |
          (unsigned long long)__builtin_bit_cast(unsigned, pv);
      __hip_atomic_store(&pbuf[frow], u, __ATOMIC_RELAXED, __HIP_MEMORY_SCOPE_AGENT);
    }
    // prefetch step inputs (non-blocking; consumed after the gather)
    float x_in = 0.f, szv = 0.f;
    if (t < TT && tid < DD) {
      x_in = XW[((size_t)b * TT + t) * DD + tid];
      if ((tid >> 6) == g) szv = SZ[((size_t)b * TT + t) * DD + tid];
    }
    // ---- overlap: ws = tape . h_prev (slot n = wv*2 + half) ----
    {
      int n = wv * 2 + (lane >> 5);
      float sw = 0.f;
      #pragma unroll
      for (int j = 0; j < 16; ++j)
        sw = fmaf(tape[n][l32 + 32 * j], h_full[l32 + 32 * j], sw);
      sw = reduce32(sw);
      if (l32 == 0) ws_arr[n] = sw * SCALE;
    }
    __syncthreads();
    // wave1 computes entmax(b) while the others start polling
    if (wv == 1) {
      float pb = entmax32(ws_arr[l32], l32);
      if (lane < NS) bArr[lane] = pb;
    }
    // ---- stamped gather: poll own element until stamp == t+1 ----
    {
      const unsigned want = (unsigned)(t + 1);
      unsigned long long u;
      do {
        u = __hip_atomic_load(&pbuf[tid], __ATOMIC_RELAXED, __HIP_MEMORY_SCOPE_AGENT);
      } while ((unsigned)(u >> 32) != want);
      float s = __builtin_bit_cast(float, (unsigned)(u & 0xFFFFFFFFu));
      if (tid < DD) hp[tid] = s + x_in + bhs[tid];
      else          wvv[tid - DD] = s;
    }
    __syncthreads();
    // ---- q1 = tape . hp (2 slots per wave);  q2 = wvv . hp (wave0) ----
    if (t < TT) {
      int n = wv * 2 + (lane >> 5);
      float s1 = 0.f;
      #pragma unroll
      for (int j = 0; j < 16; ++j)
        s1 = fmaf(tape[n][l32 + 32 * j], hp[l32 + 32 * j], s1);
      s1 = reduce32(s1);
      if (l32 == 0) q1_arr[n] = s1;
      if (wv == 0) {
        float s2 = 0.f;
        #pragma unroll
        for (int j = 0; j < 8; ++j)
          s2 = fmaf(wvv[lane + 64 * j], hp[lane + 64 * j], s2);
        s2 = reduce32(s2);
        s2 += __shfl_xor(s2, 32, 64);
        if (lane == 0) q2s = s2;
      }
    }
    __syncthreads();
    // ---- wave0: rs + entmax(a);  waves 1-15: tape update ----
    if (wv == 0) {
      if (t < TT) {
        float pb = bArr[l32];
        float rs = SCALE * fmaf(pb, q2s - q1_arr[l32], q1_arr[l32]);
        float pa = entmax32(rs, l32);
        if (lane < NS) aArr[lane] = pa;
      }
    } else {
      for (int e = tid - 64; e < NS * DD; e += 960) {
        int n = e >> 9, d = e & 511;
        float tv = tape[n][d];
        tape[n][d] = fmaf(bArr[n], wvv[d] - tv, tv);
      }
    }
    __syncthreads();
    if (t == TT) {  // final outputs
      if (tid < DD && (tid >> 6) == g) outWork[(size_t)b * DD + tid] = h_full[tid];
      for (int e = tid; e < NS * 64; e += 1024) {
        int n = e >> 6, d = g * 64 + (e & 63);
        outTape[((size_t)b * NS + n) * DD + d] = tape[n][d];
      }
      break;
    }
    // ---- read + h_t = tanh(hp + read);  Y for own slice ----
    if (tid < DD) {
      float r = 0.f;
      #pragma unroll
      for (int n = 0; n < NS; ++n) r = fmaf(aArr[n], tape[n][tid], r);
      float hn = tanhf(hp[tid] + r);
      if ((tid >> 6) == g)
        Y[((size_t)b * TT + t) * DD + tid] = hn * szv;
      h_full[tid] = hn;
    }
    __syncthreads();
  }
}

// ---------------------------------------------------------------------------
extern "C" void kernel_launch(void* const* d_in, const int* in_sizes, int n_in,
                              void* d_out, int out_size, void* d_ws, size_t ws_size,
                              hipStream_t stream) {
  (void)in_sizes; (void)n_in; (void)out_size; (void)ws_size;
  const float* x    = (const float*)d_in[0];
  const float* W_in = (const float*)d_in[1];
  const float* W_out= (const float*)d_in[2];
  const float* W_h  = (const float*)d_in[3];
  const float* W_x  = (const float*)d_in[4];
  const float* b_h  = (const float*)d_in[5];
  const float* W_wr = (const float*)d_in[6];

  float* out     = (float*)d_out;                  // [B,T,D]
  float* outTape = out + (size_t)BB * TT * DD;     // [B,NS,D]
  float* outWork = outTape + (size_t)BB * NS * DD; // [B,D]

  float* wsf  = (float*)d_ws;
  float* XP   = wsf;                               // [8192,512] (Y after scan)
  float* SZ   = XP + (size_t)BB * TT * DD;
  float* XWb  = SZ + (size_t)BB * TT * DD;
  unsigned long long* Pp = (unsigned long long*)(XWb + (size_t)BB * TT * DD); // 128 KB
  // Pp needs no init: poison stamp 0xAAAAAAAA never equals any t+1 (1..1025).

  gemm_tn<0><<<dim3(64, 8), 256, 0, stream>>>(x, W_in, XP, SZ, BB * TT, 2 * DD, DD);
  gemm_tn<1><<<dim3(64, 4), 256, 0, stream>>>(XP, W_x, XWb, nullptr, BB * TT, DD, DD);
  scan_kernel<<<64, 1024, 0, stream>>>(W_h, W_wr, b_h, XWb, SZ, XP,
                                       Pp, outTape, outWork);
  gemm_tn<1><<<dim3(64, 4), 256, 0, stream>>>(XP, W_out, out, nullptr, BB * TT, DD, DD);
}

// Round 7
// 5453.319 us; speedup vs baseline: 1.8434x; 1.1365x over previous
//
#include <hip/hip_runtime.h>

// ---------------------------------------------------------------------------
// DualMemoryLayer (entmax1.5 dual-memory scan), MI355X / gfx950
//   gemm_tn<0>: xz = x @ W_in.T -> XP = silu(lo), SZ = silu(hi)
//   gemm_tn<1>: XW = XP @ W_x.T
//   scan_kernel: 64 persistent WGs (8 per batch).  WG g owns Wh rows
//     [64g,64g+64) AND Ww rows [64g,64g+64) in registers, FULL tape replica
//     in LDS.  Exchange via self-validating stamped 8B relaxed-agent atomics
//     (R4/R6 design, HW-verified).  NEW in R7: producers publish hp finalized
//     (+xw+bh) AND local q1/q2 partial dots, so consumers skip the whole
//     post-gather dot phase; entmax sort uses DPP quad_perm for xor1/xor2.
//   gemm_tn<1>: out = Y @ W_out.T
// ---------------------------------------------------------------------------

#define BB 8
#define TT 1024
#define DD 512
#define NS 32
#define KW 8            // workgroups per batch
#define SLOTS 1288      // 1024 vector slots + 8*33 partial slots

static constexpr float SCALE = 0.044194173824159216f; // 1/sqrt(512)

__device__ __forceinline__ float siluf(float v) { return v / (1.0f + __expf(-v)); }

// ---- cross-lane helpers ----------------------------------------------------
template <int CTRL>
__device__ __forceinline__ float dpp_add(float x) {
  int xi = __builtin_bit_cast(int, x);
  int yi = __builtin_amdgcn_update_dpp(0, xi, CTRL, 0xF, 0xF, false);
  return x + __builtin_bit_cast(float, yi);
}
template <int PAT>
__device__ __forceinline__ float swz_add(float x) {
  int yi = __builtin_amdgcn_ds_swizzle(__builtin_bit_cast(int, x), PAT);
  return x + __builtin_bit_cast(float, yi);
}
// value from lane^J within 32-lane segments; DPP (VALU pipe) for J=1,2
template <int J>
__device__ __forceinline__ float xlane(float x) {
  if constexpr (J == 1) {
    int yi = __builtin_amdgcn_update_dpp(0, __builtin_bit_cast(int, x), 0xB1, 0xF, 0xF, false);
    return __builtin_bit_cast(float, yi);
  } else if constexpr (J == 2) {
    int yi = __builtin_amdgcn_update_dpp(0, __builtin_bit_cast(int, x), 0x4E, 0xF, 0xF, false);
    return __builtin_bit_cast(float, yi);
  } else {
    int yi = __builtin_amdgcn_ds_swizzle(__builtin_bit_cast(int, x), (J << 10) | 0x1F);
    return __builtin_bit_cast(float, yi);
  }
}
// direction-proof sum within each aligned 8-lane group (every lane gets it)
__device__ __forceinline__ float reduce8(float x) {
  x = swz_add<0x041F>(x); // lane ^= 1
  x = swz_add<0x081F>(x); // lane ^= 2
  x = swz_add<0x101F>(x); // lane ^= 4
  return x;
}
// sum over each 32-lane half; every lane of the half gets the sum
__device__ __forceinline__ float reduce32(float x) {
  x = dpp_add<0x121>(x);
  x = dpp_add<0x122>(x);
  x = dpp_add<0x124>(x);
  x = dpp_add<0x128>(x);
  return swz_add<0x401F>(x); // lane ^= 16
}

// ---- exact 1.5-entmax over 32 values, one per lane (width-32 segments) -----
__device__ __forceinline__ float entmax32(float z, int l32) {
  float x = 0.5f * z;
  float m = x;
  m = fmaxf(m, xlane<1>(m));  m = fmaxf(m, xlane<2>(m));
  m = fmaxf(m, xlane<4>(m));  m = fmaxf(m, xlane<8>(m));
  m = fmaxf(m, xlane<16>(m));
  x -= m;
  float s = x; // bitonic sort descending
#define XST(K, J) { float y = xlane<J>(s); bool up = (((l32 & K) == 0) ^ ((l32 & J) == 0)); s = up ? fminf(s, y) : fmaxf(s, y); }
  XST(2, 1)
  XST(4, 2)  XST(4, 1)
  XST(8, 4)  XST(8, 2)  XST(8, 1)
  XST(16, 8) XST(16, 4) XST(16, 2) XST(16, 1)
  XST(32, 16) XST(32, 8) XST(32, 4) XST(32, 2) XST(32, 1)
#undef XST
  float cs = s, cq = s * s; // inclusive prefix sums
  #pragma unroll
  for (int d = 1; d < 32; d <<= 1) {
    float ts = __shfl_up(cs, d, 32);
    float tq = __shfl_up(cq, d, 32);
    if (l32 >= d) { cs += ts; cq += tq; }
  }
  float kf    = (float)(l32 + 1);
  float mean  = cs / kf;
  float msq   = cq / kf;
  float ssv   = kf * (msq - mean * mean);
  float delta = (1.0f - ssv) / kf;
  float tau   = mean - sqrtf(fmaxf(delta, 0.0f));
  unsigned long long mask = __ballot(tau <= s);
  int support = __popcll(mask & 0xFFFFFFFFull) - 1;
  float tau_star = __shfl(tau, support, 32);
  float p = fmaxf(x - tau_star, 0.0f);
  return p * p;
}

// ---- stamped exchange primitives (R4/R6-verified) --------------------------
__device__ __forceinline__ void pubv(unsigned long long* p, int t, float v) {
  unsigned long long u = ((unsigned long long)(unsigned)(t + 1) << 32) |
                         (unsigned long long)__builtin_bit_cast(unsigned, v);
  __hip_atomic_store(p, u, __ATOMIC_RELAXED, __HIP_MEMORY_SCOPE_AGENT);
}
__device__ __forceinline__ float pollv(const unsigned long long* p, int t) {
  const unsigned want = (unsigned)(t + 1);
  unsigned long long u;
  do {
    u = __hip_atomic_load(p, __ATOMIC_RELAXED, __HIP_MEMORY_SCOPE_AGENT);
  } while ((unsigned)(u >> 32) != want);
  return __builtin_bit_cast(float, (unsigned)(u & 0xFFFFFFFFu));
}

// ---------------------------------------------------------------------------
// Tiled fp32 GEMM:  C[M,N] = A[M,K] @ B[N,K]^T
// ---------------------------------------------------------------------------
template <int MODE>
__global__ __launch_bounds__(256) void gemm_tn(const float* __restrict__ A,
                                               const float* __restrict__ Bm,
                                               float* __restrict__ C0,
                                               float* __restrict__ C1,
                                               int M, int N, int K) {
  const int bm = blockIdx.x, bn = blockIdx.y;
  const int tid = threadIdx.x;
  const int tx = tid & 15, ty = tid >> 4;
  __shared__ __align__(16) float As[16][132];
  __shared__ __align__(16) float Bs[16][132];
  float acc[8][8] = {};
  const int rowA0 = bm * 128, rowB0 = bn * 128;

  for (int k0 = 0; k0 < K; k0 += 16) {
    #pragma unroll
    for (int q = 0; q < 2; ++q) {
      int idx = tid + q * 256;
      int r   = idx >> 2;
      int kq  = (idx & 3) * 4;
      float4 a4 = *(const float4*)&A [(size_t)(rowA0 + r) * K + k0 + kq];
      float4 b4 = *(const float4*)&Bm[(size_t)(rowB0 + r) * K + k0 + kq];
      As[kq + 0][r] = a4.x; As[kq + 1][r] = a4.y; As[kq + 2][r] = a4.z; As[kq + 3][r] = a4.w;
      Bs[kq + 0][r] = b4.x; Bs[kq + 1][r] = b4.y; Bs[kq + 2][r] = b4.z; Bs[kq + 3][r] = b4.w;
    }
    __syncthreads();
    #pragma unroll
    for (int kk = 0; kk < 16; ++kk) {
      float4 a0 = *(const float4*)&As[kk][ty * 8];
      float4 a1 = *(const float4*)&As[kk][ty * 8 + 4];
      float4 b0 = *(const float4*)&Bs[kk][tx * 8];
      float4 b1 = *(const float4*)&Bs[kk][tx * 8 + 4];
      float av[8] = {a0.x, a0.y, a0.z, a0.w, a1.x, a1.y, a1.z, a1.w};
      float bv[8] = {b0.x, b0.y, b0.z, b0.w, b1.x, b1.y, b1.z, b1.w};
      #pragma unroll
      for (int i = 0; i < 8; ++i)
        #pragma unroll
        for (int j = 0; j < 8; ++j) acc[i][j] = fmaf(av[i], bv[j], acc[i][j]);
    }
    __syncthreads();
  }
  #pragma unroll
  for (int i = 0; i < 8; ++i) {
    int gr = rowA0 + ty * 8 + i;
    #pragma unroll
    for (int j = 0; j < 8; ++j) {
      int gc = rowB0 + tx * 8 + j;
      float v = acc[i][j];
      if (MODE == 0) {
        float sv = siluf(v);
        if (gc < 512) C0[(size_t)gr * 512 + gc]         = sv;
        else          C1[(size_t)gr * 512 + (gc - 512)] = sv;
      } else {
        C0[(size_t)gr * N + gc] = v;
      }
    }
  }
}

// ---------------------------------------------------------------------------
// Persistent scan.  WG (b = blk&7, g = blk>>3), 1024 threads.
// Per step:
//   matvec (own 64 d's of hp AND wvv) -> publish 128 finalized stamped values
//   -> local q1p[32]/q2p partial dots on own d-slice -> publish 33 partials
//   -> ws full-local dot -> wave1 entmax(b) while all poll/gather
//   -> wave0: q1s/q2s = sum of 8 partials, rs, entmax(a)  ||  tape update
//   -> read + h = tanh(hp + read), Y
// Slot layout per (parity,batch): [0,1024): vector s = g*128 + i (i<64 hp_d,
// else wvv_d, d = g*64 + (i&63));  [1024,1288): s = 1024 + g*33 + j
// (j<32: q1p[j], j==32: q2p).
// ---------------------------------------------------------------------------
__global__ __launch_bounds__(1024) void scan_kernel(
    const float* __restrict__ Wh, const float* __restrict__ Ww,
    const float* __restrict__ bh, const float* __restrict__ XW,
    const float* __restrict__ SZ, float* __restrict__ Y,
    unsigned long long* __restrict__ Pp,  // [2][BB][SLOTS]
    float* __restrict__ outTape, float* __restrict__ outWork) {
  const int tid  = threadIdx.x;
  const int wv   = tid >> 6, lane = tid & 63;
  const int b    = blockIdx.x & 7, g = blockIdx.x >> 3;
  const int l32  = lane & 31;
  const int seg  = tid & 7;         // column segment (8 per row)
  const int row  = tid >> 3;        // local row 0..127 (<64: Wh, else Ww)

  __shared__ float tape[NS][DD];    // full tape replica
  __shared__ float h_full[DD], hpC[DD], wvvC[DD];
  __shared__ float hp_loc[64], wv_loc[64];
  __shared__ float ws_arr[NS], q1part[KW * NS], q2part[KW];
  __shared__ float bArr[NS], aArr[NS];

  // stationary weights: 64 floats = row (Wh or Ww row g*64 + (row&63)),
  // cols seg*64..seg*64+63, bank-swizzled load order
  float w[64];
  {
    const float* src = (row < 64) ? (Wh + (size_t)(g * 64 + row) * DD)
                                  : (Ww + (size_t)(g * 64 + row - 64) * DD);
    #pragma unroll
    for (int q = 0; q < 16; ++q) {
      int c4 = seg * 64 + ((4 * q + 4 * seg) & 63);
      float4 v4 = *(const float4*)(src + c4);
      w[4*q+0] = v4.x; w[4*q+1] = v4.y; w[4*q+2] = v4.z; w[4*q+3] = v4.w;
    }
  }
  const float bhv = (seg == 0 && row < 64) ? bh[g * 64 + row] : 0.f;
  for (int e = tid; e < NS * DD; e += 1024) ((float*)tape)[e] = 0.f;
  if (tid < DD) h_full[tid] = 0.f;
  __syncthreads();

  for (int t = 0; t <= TT; ++t) {
    unsigned long long* pbuf = Pp + ((size_t)(t & 1) * BB + b) * SLOTS;
    // prefetch own-row xw and own-slice sz (latency hidden under matvec)
    float xwv = 0.f;
    if (seg == 0 && row < 64 && t < TT)
      xwv = XW[((size_t)b * TT + t) * DD + g * 64 + row];
    float szv = 0.f;
    if (t < TT && tid < DD && (tid >> 6) == g)
      szv = SZ[((size_t)b * TT + t) * DD + tid];

    // ---- row-slice matvec: pv = sum over my 64 cols of W[row]*h ----
    float pv = 0.f;
    #pragma unroll
    for (int q = 0; q < 16; ++q) {
      int c4 = seg * 64 + ((4 * q + 4 * seg) & 63);   // bank-conflict-free
      float4 h4 = *(const float4*)&h_full[c4];
      pv = fmaf(w[4*q+0], h4.x, pv);
      pv = fmaf(w[4*q+1], h4.y, pv);
      pv = fmaf(w[4*q+2], h4.z, pv);
      pv = fmaf(w[4*q+3], h4.w, pv);
    }
    pv = reduce8(pv);            // xor butterfly: every lane has the row sum
    if (seg == 0) {
      float hv = (row < 64) ? (pv + xwv + bhv) : pv;   // hp finalized
      if (row < 64) hp_loc[row] = hv; else wv_loc[row - 64] = hv;
      pubv(&pbuf[g * 128 + row], t, hv);
    }
    __syncthreads();  // SYNC1: hp_loc / wv_loc ready

    // ---- local partial dots on own d-slice (tape is pre-update) ----
    {
      int n = wv * 2 + (lane >> 5);
      float s1 = fmaf(tape[n][g * 64 + 2 * l32],     hp_loc[2 * l32],
               tape[n][g * 64 + 2 * l32 + 1] * hp_loc[2 * l32 + 1]);
      s1 = reduce32(s1);
      if (l32 == 0) pubv(&pbuf[1024 + g * 33 + n], t, s1);
      if (wv == 0 && lane < 32) {
        float s2 = fmaf(wv_loc[l32], hp_loc[l32],
                        wv_loc[l32 + 32] * hp_loc[l32 + 32]);
        s2 = reduce32(s2);
        if (l32 == 0) pubv(&pbuf[1024 + g * 33 + 32], t, s2);
      }
    }
    // ---- ws = tape . h_prev (full, local; slot n = wv*2 + half) ----
    {
      int n = wv * 2 + (lane >> 5);
      float sw = 0.f;
      #pragma unroll
      for (int j = 0; j < 16; ++j)
        sw = fmaf(tape[n][l32 + 32 * j], h_full[l32 + 32 * j], sw);
      sw = reduce32(sw);
      if (l32 == 0) ws_arr[n] = sw * SCALE;
    }
    __syncthreads();  // SYNC2

    // wave1 computes entmax(b) first; everyone then polls/gathers
    if (wv == 1) {
      float pb = entmax32(ws_arr[l32], l32);
      if (lane < NS) bArr[lane] = pb;
    }
    {
      float v = pollv(&pbuf[tid], t);
      int i = tid & 127, gg = tid >> 7;
      if (i < 64) hpC[gg * 64 + i] = v;
      else        wvvC[gg * 64 + (i - 64)] = v;
      if (tid < KW * 33) {
        float v2 = pollv(&pbuf[1024 + tid], t);
        int gg2 = tid / 33, j2 = tid - gg2 * 33;
        if (j2 < 32) q1part[gg2 * 32 + j2] = v2;
        else         q2part[gg2] = v2;
      }
    }
    __syncthreads();  // SYNC3: hpC/wvvC/partials/bArr ready

    // ---- wave0: rs from summed partials + entmax(a);  others: tape update --
    if (wv == 0) {
      if (t < TT) {
        float q1s = 0.f, q2s = 0.f;
        #pragma unroll
        for (int k = 0; k < KW; ++k) {
          q1s += q1part[k * 32 + l32];
          q2s += q2part[k];
        }
        float pb = bArr[l32];
        float rs = SCALE * fmaf(pb, q2s - q1s, q1s);
        float pa = entmax32(rs, l32);
        if (lane < NS) aArr[lane] = pa;
      }
    } else {
      for (int e = tid - 64; e < NS * DD / 4; e += 960) {
        int n = e >> 7, dq = (e & 127) * 4;
        float  bn = bArr[n];
        float4 tv = *(float4*)&tape[n][dq];
        float4 wq = *(const float4*)&wvvC[dq];
        tv.x = fmaf(bn, wq.x - tv.x, tv.x);
        tv.y = fmaf(bn, wq.y - tv.y, tv.y);
        tv.z = fmaf(bn, wq.z - tv.z, tv.z);
        tv.w = fmaf(bn, wq.w - tv.w, tv.w);
        *(float4*)&tape[n][dq] = tv;
      }
    }
    __syncthreads();  // SYNC4: aArr + tape_new ready

    if (t == TT) {  // final outputs: tape_T and h_{T-1}
      if (tid < DD && (tid >> 6) == g) outWork[(size_t)b * DD + tid] = h_full[tid];
      for (int e = tid; e < NS * 64; e += 1024) {
        int n = e >> 6, d = g * 64 + (e & 63);
        outTape[((size_t)b * NS + n) * DD + d] = tape[n][d];
      }
      break;
    }
    // ---- read + h_t = tanh(hp + read);  Y for own slice ----
    if (tid < DD) {
      float r = 0.f;
      #pragma unroll
      for (int n = 0; n < NS; ++n) r = fmaf(aArr[n], tape[n][tid], r);
      float hn = tanhf(hpC[tid] + r);
      if ((tid >> 6) == g)
        Y[((size_t)b * TT + t) * DD + tid] = hn * szv;
      h_full[tid] = hn;
    }
    __syncthreads();  // SYNC5
  }
}

// ---------------------------------------------------------------------------
extern "C" void kernel_launch(void* const* d_in, const int* in_sizes, int n_in,
                              void* d_out, int out_size, void* d_ws, size_t ws_size,
                              hipStream_t stream) {
  (void)in_sizes; (void)n_in; (void)out_size; (void)ws_size;
  const float* x    = (const float*)d_in[0];
  const float* W_in = (const float*)d_in[1];
  const float* W_out= (const float*)d_in[2];
  const float* W_h  = (const float*)d_in[3];
  const float* W_x  = (const float*)d_in[4];
  const float* b_h  = (const float*)d_in[5];
  const float* W_wr = (const float*)d_in[6];

  float* out     = (float*)d_out;                  // [B,T,D]
  float* outTape = out + (size_t)BB * TT * DD;     // [B,NS,D]
  float* outWork = outTape + (size_t)BB * NS * DD; // [B,D]

  float* wsf  = (float*)d_ws;
  float* XP   = wsf;                               // [8192,512] (Y after scan)
  float* SZ   = XP + (size_t)BB * TT * DD;
  float* XWb  = SZ + (size_t)BB * TT * DD;
  unsigned long long* Pp = (unsigned long long*)(XWb + (size_t)BB * TT * DD);
  // Pp: [2][BB][SLOTS] = 161 KB.  No init needed: 0xAA poison stamp never
  // equals any wanted stamp t+1 (1..1025).

  gemm_tn<0><<<dim3(64, 8), 256, 0, stream>>>(x, W_in, XP, SZ, BB * TT, 2 * DD, DD);
  gemm_tn<1><<<dim3(64, 4), 256, 0, stream>>>(XP, W_x, XWb, nullptr, BB * TT, DD, DD);
  scan_kernel<<<64, 1024, 0, stream>>>(W_h, W_wr, b_h, XWb, SZ, XP,
                                       Pp, outTape, outWork);
  gemm_tn<1><<<dim3(64, 4), 256, 0, stream>>>(XP, W_out, out, nullptr, BB * TT, DD, DD);
}